// Round 6
// baseline (3075.179 us; speedup 1.0000x reference)
//
#include <hip/hip_runtime.h>
#include <hip/hip_bf16.h>

#define N_PTS 16384
#define KNN   20
#define LIST  32   // approx-stage list width per candidate-quarter (refine is exact)
#define NSPLIT 4   // candidate-range split

typedef unsigned int u32;
typedef const __attribute__((address_space(1))) u32 glob_u32;
typedef __attribute__((address_space(3))) u32 lds_u32;

typedef __attribute__((ext_vector_type(8))) short bf16x8;
typedef __attribute__((ext_vector_type(4))) float f32x4;

__device__ __forceinline__ void g2lds16(const void* g, void* l) {
  // async global->LDS, 16B per lane; LDS dest = wave-uniform base + lane*16
  __builtin_amdgcn_global_load_lds((glob_u32*)g, (lds_u32*)l, 16, 0, 0);
}

// Stage ROWS x F bf16 from X[row0..) into LDS with chunk-XOR swizzle:
// LDS 16B-chunk position p of row r holds global chunk (p ^ (r & (NCH-1))).
template<int F, int ROWS>
__device__ __forceinline__ void stage_c(const ushort* __restrict__ X, int row0, ushort* dst) {
  constexpr int NCH = F / 8;            // 16B chunks per row
  constexpr int TOT = ROWS * NCH;       // >= 256 for all instantiations
  const int tid = threadIdx.x;
  const int wv = tid >> 6, ln = tid & 63;
#pragma unroll
  for (int base = 0; base < TOT; base += 256) {
    int g = base + wv * 64 + ln;
    int r = g / NCH;
    int p = g & (NCH - 1);
    int sc = p ^ (r & (NCH - 1));       // pre-swizzled global source chunk
    g2lds16(X + (size_t)(row0 + r) * F + sc * 8,
            dst + (size_t)(base + wv * 64) * 8);   // wave-uniform LDS base
  }
}

// Load one 16x32 bf16 MFMA fragment from a swizzled LDS tile.
// lane: row = rbase + (ln&15), k-chunk pc = kc*4 + (ln>>4), de-swizzled.
template<int F>
__device__ __forceinline__ bf16x8 ldfrag(const ushort* buf, int rbase, int kc, int ln) {
  constexpr int NCH = F / 8;
  int r  = rbase + (ln & 15);
  int pc = kc * 4 + (ln >> 4);
  int sp = pc ^ (r & (NCH - 1));
  return *(const bf16x8*)(buf + (size_t)r * F + sp * 8);
}

// Fused bf16x3-MFMA distance + buffered top-32 kNN over a QUARTER of the
// candidate range. 256 thr = 4 waves; wave owns 16 queries; 32-cand tiles.
// Sorted lists live in REGISTERS (lane j<32 holds entry j of query k in
// ld_d[k]/ld_i[k]); survivors append in parallel to LDS buffers; rare
// wave-collective bitonic-64 merges fold buffer into the register lists.
template<int F>
__global__ __launch_bounds__(256) void knn_kernel(const ushort* __restrict__ Xh,
                                                  const ushort* __restrict__ Xl,
                                                  const float* __restrict__ sqn,
                                                  int* __restrict__ out_cand) {
  constexpr int KC = F / 32;            // 32-k chunks per row
  constexpr int NC = N_PTS / NSPLIT;    // candidates per block
  constexpr int TS = 32;                // candidate tile size
  constexpr int NT = NC / TS;
  extern __shared__ ushort lds_raw[];
  ushort* cb  = lds_raw;                          // [2 buf][2 part][TS*F]
  float*  Bs  = (float*)(cb + 4 * TS * F);        // 64*32 survivor scores
  ushort* Bi  = (ushort*)(Bs + 64 * LIST);        // 64*32 survivor indices

  const int tid = threadIdx.x;
  const int wv = tid >> 6, ln = tid & 63;
  const int q0 = (blockIdx.x >> 2) * 64;
  const int hf = blockIdx.x & 3;
  const int cbase = hf * NC;

  // register-resident sorted lists: lane j<32 holds entry j of query k
  float ld_d[16];
  int   ld_i[16];
#pragma unroll
  for (int k = 0; k < 16; ++k) { ld_d[k] = 3.0e38f; ld_i[k] = 0; }
  float thr_reg = 3.0e38f;   // lane l<16: 32nd-best for query wv*16+l
  float myth[4];             // this lane's own-query thresholds, myth[r] for q=(ln>>4)*4+r
#pragma unroll
  for (int r = 0; r < 4; ++r) myth[r] = 3.0e38f;
  int bcnt = 0;              // lane l<16: buffered-survivor count of query wv*16+l

  // stage query tile (64 rows hi + 64 rows lo fills the whole cand dbuf space)
  stage_c<F, 64>(Xh, q0, cb);
  stage_c<F, 64>(Xl, q0, cb + 64 * F);
  __syncthreads();
  bf16x8 ah[KC], al[KC];
#pragma unroll
  for (int kc = 0; kc < KC; ++kc) {
    ah[kc] = ldfrag<F>(cb, wv * 16, kc, ln);
    al[kc] = ldfrag<F>(cb + 64 * F, wv * 16, kc, ln);
  }
  __syncthreads();  // A-frag ds_reads drained before overwriting
  stage_c<F, TS>(Xh, cbase, cb);
  stage_c<F, TS>(Xl, cbase, cb + TS * F);
  __syncthreads();  // tile 0 resident

  for (int t = 0; t < NT; ++t) {
    const int c0 = t * TS;
    float cn[2];
#pragma unroll
    for (int cg = 0; cg < 2; ++cg) cn[cg] = sqn[cbase + c0 + cg * 16 + (ln & 15)];

    // prefetch next tile (drained by end-of-loop barrier)
    if (t + 1 < NT) {
      ushort* nb = cb + (size_t)((t + 1) & 1) * (2 * TS * F);
      stage_c<F, TS>(Xh, cbase + (t + 1) * TS, nb);
      stage_c<F, TS>(Xl, cbase + (t + 1) * TS, nb + TS * F);
    }

    const ushort* hi = cb + (size_t)(t & 1) * (2 * TS * F);
    const ushort* lo = hi + TS * F;

    // bf16x3 MFMA: hi*hi and cross terms as independent chains
    f32x4 aH[2], aX[2];
#pragma unroll
    for (int cg = 0; cg < 2; ++cg) { aH[cg] = (f32x4){0,0,0,0}; aX[cg] = (f32x4){0,0,0,0}; }
#pragma unroll
    for (int kc = 0; kc < KC; ++kc) {
      bf16x8 bh0 = ldfrag<F>(hi, 0,  kc, ln);
      bf16x8 bh1 = ldfrag<F>(hi, 16, kc, ln);
      bf16x8 bl0 = ldfrag<F>(lo, 0,  kc, ln);
      bf16x8 bl1 = ldfrag<F>(lo, 16, kc, ln);
      aH[0] = __builtin_amdgcn_mfma_f32_16x16x32_bf16(ah[kc], bh0, aH[0], 0, 0, 0);
      aH[1] = __builtin_amdgcn_mfma_f32_16x16x32_bf16(ah[kc], bh1, aH[1], 0, 0, 0);
      aX[0] = __builtin_amdgcn_mfma_f32_16x16x32_bf16(al[kc], bh0, aX[0], 0, 0, 0);
      aX[1] = __builtin_amdgcn_mfma_f32_16x16x32_bf16(al[kc], bh1, aX[1], 0, 0, 0);
      aX[0] = __builtin_amdgcn_mfma_f32_16x16x32_bf16(ah[kc], bl0, aX[0], 0, 0, 0);
      aX[1] = __builtin_amdgcn_mfma_f32_16x16x32_bf16(ah[kc], bl1, aX[1], 0, 0, 0);
    }

    // selection: parallel appends per (cg, r) ballot group
#pragma unroll
    for (int cg = 0; cg < 2; ++cg) {
#pragma unroll
      for (int r = 0; r < 4; ++r) {
        // lane scores query (ln>>4)*4+r vs candidate c0+cg*16+(ln&15)
        float s = cn[cg] - 2.0f * (aH[cg][r] + aX[cg][r]);
        unsigned long long m = __ballot(s < myth[r]);
        if (m) {
          int qk = ((ln & 48) >> 2) + r;            // (ln>>4)*4 + r
          int basec = __shfl(bcnt, qk);
          if (s < myth[r]) {
            int pos = basec +
                __popcll(m & (0xFFFFull << (ln & 48)) & ((1ull << ln) - 1));
            int brow = (wv * 16 + qk) * LIST;
            Bs[brow + pos] = s;
            Bi[brow + pos] = (ushort)(cbase + c0 + cg * 16 + (ln & 15));
          }
          if (ln < 16 && (ln & 3) == r)
            bcnt += __popcll((m >> ((ln >> 2) * 16)) & 0xFFFFull);
        }
      }
      // overflow merges: post-cg counts <= 32 (=cap); fold any > 16
      unsigned long long mm = __ballot(ln < 16 && bcnt > 16);
      if (mm) {
#pragma unroll
        for (int k = 0; k < 16; ++k) {
          if ((mm >> k) & 1) {
            int cnt = __shfl(bcnt, k);
            int brow = (wv * 16 + k) * LIST;
            float key; int id;
            if (ln < 32) { key = ld_d[k]; id = ld_i[k]; }
            else {
              int j = ln - 32;
              bool v = j < cnt;
              key = v ? Bs[brow + j] : 3.0e38f;
              id  = v ? (int)Bi[brow + j] : 65535;
            }
#pragma unroll
            for (int kk = 2; kk <= 64; kk <<= 1) {
#pragma unroll
              for (int jj = kk >> 1; jj > 0; jj >>= 1) {
                float ok = __shfl_xor(key, jj);
                int   oi = __shfl_xor(id, jj);
                bool pless = (ok < key) || (ok == key && oi < id);
                bool take = pless == (((ln & jj) == 0) == ((ln & kk) == 0));
                key = take ? ok : key;
                id  = take ? oi : id;
              }
            }
            if (ln < 32) { ld_d[k] = key; ld_i[k] = id; }
            float tnew = __shfl(key, 31);
            thr_reg = (ln == k) ? tnew : thr_reg;
            bcnt    = (ln == k) ? 0 : bcnt;
          }
        }
#pragma unroll
        for (int rr = 0; rr < 4; ++rr) myth[rr] = __shfl(thr_reg, ((ln & 48) >> 2) + rr);
      }
    }
    __syncthreads();  // drains next-tile stage; protects c-buffers
  }

  // final flush of remaining buffered survivors
  {
    unsigned long long mm = __ballot(ln < 16 && bcnt > 0);
    if (mm) {
#pragma unroll
      for (int k = 0; k < 16; ++k) {
        if ((mm >> k) & 1) {
          int cnt = __shfl(bcnt, k);
          int brow = (wv * 16 + k) * LIST;
          float key; int id;
          if (ln < 32) { key = ld_d[k]; id = ld_i[k]; }
          else {
            int j = ln - 32;
            bool v = j < cnt;
            key = v ? Bs[brow + j] : 3.0e38f;
            id  = v ? (int)Bi[brow + j] : 65535;
          }
#pragma unroll
          for (int kk = 2; kk <= 64; kk <<= 1) {
#pragma unroll
            for (int jj = kk >> 1; jj > 0; jj >>= 1) {
              float ok = __shfl_xor(key, jj);
              int   oi = __shfl_xor(id, jj);
              bool pless = (ok < key) || (ok == key && oi < id);
              bool take = pless == (((ln & jj) == 0) == ((ln & kk) == 0));
              key = take ? ok : key;
              id  = take ? oi : id;
            }
          }
          if (ln < 32) { ld_d[k] = key; ld_i[k] = id; }
        }
      }
    }
  }

#pragma unroll
  for (int k = 0; k < 16; ++k) {
    if (ln < LIST)
      out_cand[(size_t)(q0 + wv * 16 + k) * (NSPLIT * LIST) + hf * LIST + ln] = ld_i[k];
  }
}

// Exact fp32 re-rank of the 128 union candidates -> true fp32 top-20 set.
// One wave per query; lane l handles candidates l and l+64.
template<int F>
__global__ __launch_bounds__(256) void refine_kernel(const float* __restrict__ X,
                                                     const float* __restrict__ sqn,
                                                     const int* __restrict__ cand,
                                                     int* __restrict__ out_idx) {
  constexpr int CW = NSPLIT * LIST;  // 128
  const int wv = threadIdx.x >> 6, ln = threadIdx.x & 63;
  const int q = blockIdx.x * 4 + wv;
  int c0 = cand[(size_t)q * CW + ln];
  int c1 = cand[(size_t)q * CW + 64 + ln];
  const float* qrow = X + (size_t)q * F;
  const float* crow0 = X + (size_t)c0 * F;
  const float* crow1 = X + (size_t)c1 * F;
  float dot0 = 0.f, dot1 = 0.f;
#pragma unroll
  for (int d = 0; d < F; d += 4) {
    float4 qv = *(const float4*)(qrow + d);
    float4 v0 = *(const float4*)(crow0 + d);
    float4 v1 = *(const float4*)(crow1 + d);
    dot0 += qv.x * v0.x + qv.y * v0.y + qv.z * v0.z + qv.w * v0.w;
    dot1 += qv.x * v1.x + qv.y * v1.y + qv.z * v1.z + qv.w * v1.w;
  }
  float s0 = sqn[c0] - 2.0f * dot0;
  float s1 = sqn[c1] - 2.0f * dot1;
  // rank by (score asc, index asc); quarters are disjoint -> no duplicates
  int rank0 = 0, rank1 = 0;
#pragma unroll 1
  for (int j = 0; j < 64; ++j) {
    float a0 = __shfl(s0, j); int i0 = __shfl(c0, j);
    float a1 = __shfl(s1, j); int i1 = __shfl(c1, j);
    rank0 += ((a0 < s0) || (a0 == s0 && i0 < c0)) + ((a1 < s0) || (a1 == s0 && i1 < c0));
    rank1 += ((a0 < s1) || (a0 == s1 && i0 < c1)) + ((a1 < s1) || (a1 == s1 && i1 < c1));
  }
  if (rank0 < KNN) out_idx[(size_t)q * KNN + rank0] = c0;
  if (rank1 < KNN) out_idx[(size_t)q * KNN + rank1] = c1;
}

// x1 = relu(pos @ W1 + b1) + bf16 hi/lo split + squared row norms.
__global__ __launch_bounds__(256) void mlp1_kernel(const float* __restrict__ pos,
                                                   const float* __restrict__ W1,
                                                   const float* __restrict__ b1,
                                                   float* __restrict__ x1,
                                                   ushort* __restrict__ xh,
                                                   ushort* __restrict__ xl,
                                                   float* __restrict__ sqn) {
  int i = blockIdx.x * 4 + (threadIdx.x >> 6);
  int o = threadIdx.x & 63;
  float p0 = pos[i * 3], p1 = pos[i * 3 + 1], p2 = pos[i * 3 + 2];
  float v = p0 * W1[o] + p1 * W1[64 + o] + p2 * W1[128 + o] + b1[o];
  v = fmaxf(v, 0.f);
  x1[(size_t)i * 64 + o] = v;
  __hip_bfloat16 h = __float2bfloat16(v);
  float hv = __bfloat162float(h);
  __hip_bfloat16 l2 = __float2bfloat16(v - hv);
  xh[(size_t)i * 64 + o] = *(ushort*)&h;
  xl[(size_t)i * 64 + o] = *(ushort*)&l2;
  float ss = v * v;
#pragma unroll
  for (int d = 32; d; d >>= 1) ss += __shfl_xor(ss, d);
  if (o == 0) sqn[i] = ss;
}

// hi/lo bf16 split + squared norms for an existing fp32 feature array.
template<int F>
__global__ __launch_bounds__(256) void prep_kernel(const float* __restrict__ x,
                                                   ushort* __restrict__ xh,
                                                   ushort* __restrict__ xl,
                                                   float* __restrict__ sqn) {
  int i = blockIdx.x * 4 + (threadIdx.x >> 6);
  int l = threadIdx.x & 63;
  float ss = 0.f;
#pragma unroll
  for (int d = l; d < F; d += 64) {
    float v = x[(size_t)i * F + d];
    ss += v * v;
    __hip_bfloat16 h = __float2bfloat16(v);
    float hv = __bfloat162float(h);
    __hip_bfloat16 l2 = __float2bfloat16(v - hv);
    xh[(size_t)i * F + d] = *(ushort*)&h;
    xl[(size_t)i * F + d] = *(ushort*)&l2;
  }
#pragma unroll
  for (int d = 32; d; d >>= 1) ss += __shfl_xor(ss, d);
  if (l == 0) sqn[i] = ss;
}

// C[N x OUT] = X[N x K] @ W[K x OUT] (+ bias). Register-tiled 4 rows x float4.
template<int K, int OUT, bool BIAS>
__global__ __launch_bounds__(256) void lin_kernel(const float* __restrict__ X,
                                                  const float* __restrict__ W,
                                                  const float* __restrict__ bias,
                                                  float* __restrict__ C) {
  constexpr int XD = OUT / 4;
  constexpr int YD = 256 / XD;
  constexpr int R = YD * 4;
  __shared__ float xs[R * K];
  const int tid = threadIdx.x;
  const int tx = tid % XD, ty = tid / XD;
  const size_t r0 = (size_t)blockIdx.x * R;
  const float4* Xv = (const float4*)(X + r0 * K);
  float4* xsv = (float4*)xs;
#pragma unroll
  for (int i2 = tid; i2 < R * K / 4; i2 += 256) xsv[i2] = Xv[i2];
  __syncthreads();
  float4 acc[4];
#pragma unroll
  for (int i = 0; i < 4; i++) acc[i] = make_float4(0.f, 0.f, 0.f, 0.f);
  const float4* W4 = (const float4*)W;
#pragma unroll 8
  for (int k = 0; k < K; ++k) {
    float4 wv = W4[k * XD + tx];
#pragma unroll
    for (int i = 0; i < 4; i++) {
      float xv = xs[(ty * 4 + i) * K + k];
      acc[i].x += xv * wv.x; acc[i].y += xv * wv.y;
      acc[i].z += xv * wv.z; acc[i].w += xv * wv.w;
    }
  }
  float4 bv = make_float4(0.f, 0.f, 0.f, 0.f);
  if (BIAS) bv = ((const float4*)bias)[tx];
#pragma unroll
  for (int i = 0; i < 4; i++) {
    float4 o;
    o.x = acc[i].x + bv.x; o.y = acc[i].y + bv.y;
    o.z = acc[i].z + bv.z; o.w = acc[i].w + bv.w;
    ((float4*)(C + (r0 + ty * 4 + i) * OUT))[tx] = o;
  }
}

// out_i = relu(P_i + max_j Q[idx[i][j]])
template<int OUT>
__global__ void maxpool_kernel(const float* __restrict__ P, const float* __restrict__ Q,
                               const int* __restrict__ idx, float* __restrict__ xo) {
  __shared__ int nb[KNN];
  int i = blockIdx.x;
  if (threadIdx.x < KNN) nb[threadIdx.x] = idx[(size_t)i * KNN + threadIdx.x];
  __syncthreads();
  int o = threadIdx.x;
  float m = -3.0e38f;
#pragma unroll
  for (int j = 0; j < KNN; j++) m = fmaxf(m, Q[(size_t)nb[j] * OUT + o]);
  float p = P[(size_t)i * OUT + o];
  xo[(size_t)i * OUT + o] = fmaxf(p + m, 0.f);
}

// Wp[k][o] = We[k][o] - We[K+k][o]
__global__ void wsub_kernel(const float* __restrict__ We, float* __restrict__ Wp, int total) {
  int t = blockIdx.x * 256 + threadIdx.x;
  if (t < total) Wp[t] = We[t] - We[total + t];
}

extern "C" void kernel_launch(void* const* d_in, const int* in_sizes, int n_in,
                              void* d_out, int out_size, void* d_ws, size_t ws_size,
                              hipStream_t stream) {
  const float* pos = (const float*)d_in[0];
  const float* W1  = (const float*)d_in[1];
  const float* b1  = (const float*)d_in[2];
  const float* We1 = (const float*)d_in[3];
  const float* be1 = (const float*)d_in[4];
  const float* We2 = (const float*)d_in[5];
  const float* be2 = (const float*)d_in[6];
  const float* W2  = (const float*)d_in[7];
  const float* b2  = (const float*)d_in[8];
  float* out = (float*)d_out;

  const size_t N = N_PTS;
  float* ws  = (float*)d_ws;
  float* x1  = ws;               // N*64
  float* P1  = x1 + N * 64;      // N*128
  float* Q1  = P1 + N * 128;     // N*128
  float* x2  = Q1 + N * 128;     // N*128
  float* P2  = x2 + N * 128;     // N*256
  float* Q2  = P2 + N * 256;     // N*256
  float* x3  = Q2 + N * 256;     // N*256
  float* sqn = x3 + N * 256;     // N (x1 norms, then x2 norms)
  float* Wp1 = sqn + N;          // 64*128
  float* Wp2 = Wp1 + 64 * 128;   // 128*256
  int* idx1  = (int*)(Wp2 + 128 * 256);  // N*20
  int* idx2  = idx1 + N * KNN;           // N*20
  // cand aliases Q2's slot: cand is fully consumed by refine before Q2 is
  // written by lin_kernel (same stream, program order).
  int* cand  = (int*)Q2;                 // N*128
  ushort* X1h = (ushort*)(idx2 + N * KNN);  // N*64
  ushort* X1l = X1h + N * 64;               // N*64
  ushort* X2h = X1l + N * 64;               // N*128
  ushort* X2l = X2h + N * 128;              // N*128
  size_t need = (size_t)((char*)(X2l + N * 128) - (char*)d_ws);
  if (ws_size < need) return;  // insufficient scratch -> visible failure

  auto lds_bytes = [](int F) {
    // cand dbuf (2 buf x 2 part x 32 rows) + Bs + Bi
    return (size_t)(4 * 32 * F) * 2 +
           (size_t)(64 * LIST) * 4 + (size_t)(64 * LIST) * 2;
  };
  size_t lds64 = lds_bytes(64), lds128 = lds_bytes(128);
  hipFuncSetAttribute(reinterpret_cast<const void*>(&knn_kernel<64>),
                      hipFuncAttributeMaxDynamicSharedMemorySize, (int)lds64);
  hipFuncSetAttribute(reinterpret_cast<const void*>(&knn_kernel<128>),
                      hipFuncAttributeMaxDynamicSharedMemorySize, (int)lds128);

  wsub_kernel<<<(64 * 128 + 255) / 256, 256, 0, stream>>>(We1, Wp1, 64 * 128);
  wsub_kernel<<<(128 * 256 + 255) / 256, 256, 0, stream>>>(We2, Wp2, 128 * 256);

  mlp1_kernel<<<N / 4, 256, 0, stream>>>(pos, W1, b1, x1, X1h, X1l, sqn);
  knn_kernel<64><<<(N / 64) * NSPLIT, 256, lds64, stream>>>(X1h, X1l, sqn, cand);
  refine_kernel<64><<<N / 4, 256, 0, stream>>>(x1, sqn, cand, idx1);
  lin_kernel<64, 128, true ><<<N / 32, 256, 0, stream>>>(x1, Wp1, be1, P1);
  lin_kernel<64, 128, false><<<N / 32, 256, 0, stream>>>(x1, We1 + 64 * 128, nullptr, Q1);
  maxpool_kernel<128><<<N, 128, 0, stream>>>(P1, Q1, idx1, x2);

  prep_kernel<128><<<N / 4, 256, 0, stream>>>(x2, X2h, X2l, sqn);
  knn_kernel<128><<<(N / 64) * NSPLIT, 256, lds128, stream>>>(X2h, X2l, sqn, cand);
  refine_kernel<128><<<N / 4, 256, 0, stream>>>(x2, sqn, cand, idx2);
  lin_kernel<128, 256, true ><<<N / 16, 256, 0, stream>>>(x2, Wp2, be2, P2);
  lin_kernel<128, 256, false><<<N / 16, 256, 0, stream>>>(x2, We2 + 128 * 256, nullptr, Q2);
  maxpool_kernel<256><<<N, 256, 0, stream>>>(P2, Q2, idx2, x3);

  lin_kernel<256, 128, true ><<<N / 32, 256, 0, stream>>>(x3, W2, b2, out);
}

// Round 7
// 2136.579 us; speedup vs baseline: 1.4393x; 1.4393x over previous
//
#include <hip/hip_runtime.h>
#include <hip/hip_bf16.h>

#define N_PTS 16384
#define KNN   20
#define LIST  32   // approx-stage list width per candidate-half (refine is exact)

typedef unsigned int u32;
typedef const __attribute__((address_space(1))) u32 glob_u32;
typedef __attribute__((address_space(3))) u32 lds_u32;

typedef __attribute__((ext_vector_type(8))) short bf16x8;
typedef __attribute__((ext_vector_type(4))) float f32x4;

__device__ __forceinline__ void g2lds16(const void* g, void* l) {
  // async global->LDS, 16B per lane; LDS dest = wave-uniform base + lane*16
  __builtin_amdgcn_global_load_lds((glob_u32*)g, (lds_u32*)l, 16, 0, 0);
}

template<int N>
__device__ __forceinline__ void wait_vm() {
  if constexpr (N == 0) asm volatile("s_waitcnt vmcnt(0)" ::: "memory");
  else if constexpr (N == 3) asm volatile("s_waitcnt vmcnt(3)" ::: "memory");
  else if constexpr (N == 5) asm volatile("s_waitcnt vmcnt(5)" ::: "memory");
}

// Stage ROWS x F bf16 from X[row0..) into LDS with chunk-XOR swizzle:
// LDS 16B-chunk position p of row r holds global chunk (p ^ (r & (NCH-1))).
template<int F, int ROWS>
__device__ __forceinline__ void stage_c(const ushort* __restrict__ X, int row0, ushort* dst) {
  constexpr int NCH = F / 8;            // 16B chunks per row
  constexpr int TOT = ROWS * NCH;       // >= 256 for all instantiations
  const int tid = threadIdx.x;
  const int wv = tid >> 6, ln = tid & 63;
#pragma unroll
  for (int base = 0; base < TOT; base += 256) {
    int g = base + wv * 64 + ln;
    int r = g / NCH;
    int p = g & (NCH - 1);
    int sc = p ^ (r & (NCH - 1));       // pre-swizzled global source chunk
    g2lds16(X + (size_t)(row0 + r) * F + sc * 8,
            dst + (size_t)(base + wv * 64) * 8);   // wave-uniform LDS base
  }
}

// Load one 16x32 bf16 MFMA fragment from a swizzled LDS tile.
template<int F>
__device__ __forceinline__ bf16x8 ldfrag(const ushort* buf, int rbase, int kc, int ln) {
  constexpr int NCH = F / 8;
  int r  = rbase + (ln & 15);
  int pc = kc * 4 + (ln >> 4);
  int sp = pc ^ (r & (NCH - 1));
  return *(const bf16x8*)(buf + (size_t)r * F + sp * 8);
}

// Fused bf16x3-MFMA distance + buffered top-32 kNN over HALF the candidate
// range. 4 waves; wave owns 16 queries; 32-cand tiles; TRIPLE-buffered with
// prefetch depth 2, counted vmcnt, raw s_barrier (loads stay in flight across
// barriers). Candidate norms ride the DMA stage so per-wave VMEM counts are
// exact. Selection: parallel appends + rare wave-collective bitonic merges.
template<int F>
__global__ __launch_bounds__(256) void knn_kernel(const ushort* __restrict__ Xh,
                                                  const ushort* __restrict__ Xl,
                                                  const float* __restrict__ sqn,
                                                  int* __restrict__ out_cand) {
  constexpr int KC = F / 32;            // 32-k chunks per row
  constexpr int NC = N_PTS / 2;         // candidates per block (2-way split)
  constexpr int TS = 32;                // candidate tile size
  constexpr int NT = NC / TS;
  constexpr int SLOT = 2 * TS * F;      // ushorts per buffer slot (hi+lo)
  constexpr int LPSN = F / 32 + 1;      // VMEM instrs per stage per thread
  extern __shared__ ushort lds_raw[];
  ushort* cb  = lds_raw;                          // 3 slots x SLOT
  float* nlds = (float*)(cb + 3 * SLOT);          // 3 x 32 candidate norms
  float*  Bs  = nlds + 96;                        // 64*32 survivor scores
  ushort* Bi  = (ushort*)(Bs + 64 * LIST);        // 64*32 survivor indices
  float*  Ld  = (float*)(Bi + 64 * LIST);         // 64*32 sorted distances
  ushort* Li  = (ushort*)(Ld + 64 * LIST);        // 64*32 sorted indices

  const int tid = threadIdx.x;
  const int wv = tid >> 6, ln = tid & 63;
  const int q0 = (blockIdx.x >> 1) * 64;
  const int hf = blockIdx.x & 1;
  const int cbase = hf * NC;

  // init per-query sorted lists (wave-local rows)
#pragma unroll
  for (int k = 0; k < 16; ++k) {
    int row = (wv * 16 + k) * LIST;
    if (ln < LIST) { Ld[row + ln] = 3.0e38f; Li[row + ln] = 0; }
  }
  float thr_reg = 3.0e38f;   // lane l<16: 32nd-best for query wv*16+l
  float myth[4];             // own-query thresholds, myth[r] for q=(ln>>4)*4+r
#pragma unroll
  for (int r = 0; r < 4; ++r) myth[r] = 3.0e38f;
  int bcnt = 0;              // lane l<16: buffered count of query wv*16+l

  // wave-collective merge of query qk's buffer into its sorted top-32
  auto merge_q = [&](int qk) {
    int cnt = __shfl(bcnt, qk);
    int lrow = (wv * 16 + qk) * LIST;
    float key; int id;
    if (ln < 32) { key = Ld[lrow + ln]; id = (int)Li[lrow + ln]; }
    else {
      int j = ln - 32;
      bool v = j < cnt;
      key = v ? Bs[lrow + j] : 3.0e38f;
      id  = v ? (int)Bi[lrow + j] : 65535;
    }
#pragma unroll
    for (int kk = 2; kk <= 64; kk <<= 1) {
#pragma unroll
      for (int jj = kk >> 1; jj > 0; jj >>= 1) {
        float ok = __shfl_xor(key, jj);
        int   oi = __shfl_xor(id, jj);
        bool pless = (ok < key) || (ok == key && oi < id);
        bool take = pless == (((ln & jj) == 0) == ((ln & kk) == 0));
        key = take ? ok : key;
        id  = take ? oi : id;
      }
    }
    if (ln < 32) { Ld[lrow + ln] = key; Li[lrow + ln] = (ushort)id; }
    float tnew = __shfl(key, 31);
    thr_reg = (ln == qk) ? tnew : thr_reg;
    bcnt    = (ln == qk) ? 0 : bcnt;
  };

  // ---- prologue: stage query tile (slots 0+1), pull A frags to registers
  stage_c<F, 64>(Xh, q0, cb);
  stage_c<F, 64>(Xl, q0, cb + 64 * F);
  __syncthreads();
  bf16x8 ah[KC], al[KC];
#pragma unroll
  for (int kc = 0; kc < KC; ++kc) {
    ah[kc] = ldfrag<F>(cb, wv * 16, kc, ln);
    al[kc] = ldfrag<F>(cb + 64 * F, wv * 16, kc, ln);
  }
  asm volatile("s_waitcnt lgkmcnt(0)" ::: "memory");
  __syncthreads();  // frags consumed; buffer slots free

  // stage tiles 0 and 1 (slots 0,1) incl. norms; drain tile 0 only
#pragma unroll
  for (int t0 = 0; t0 < 2; ++t0) {
    const int row0 = cbase + t0 * TS;
    stage_c<F, TS>(Xh, row0, cb + t0 * SLOT);
    stage_c<F, TS>(Xl, row0, cb + t0 * SLOT + TS * F);
    if (ln < 8) g2lds16(sqn + row0 + ln * 4, nlds + t0 * 32);
  }
  wait_vm<LPSN>();  // stage(0) complete; stage(1) still in flight

  // ---- main loop: depth-2 pipeline, raw barriers, counted vmcnt
#pragma unroll 1
  for (int t = 0; t < NT; ++t) {
    __builtin_amdgcn_s_barrier();       // stage(t) visible; slot (t+2)%3 free
    asm volatile("" ::: "memory");
    if (t + 2 < NT) {
      const int sl2 = (t + 2) % 3;
      const int row0 = cbase + (t + 2) * TS;
      stage_c<F, TS>(Xh, row0, cb + sl2 * SLOT);
      stage_c<F, TS>(Xl, row0, cb + sl2 * SLOT + TS * F);
      if (ln < 8) g2lds16(sqn + row0 + ln * 4, nlds + sl2 * 32);
    }
    const int sl = t % 3;
    const int c0 = t * TS;
    const ushort* hi = cb + sl * SLOT;
    const ushort* lo = hi + TS * F;
    float cn0 = nlds[sl * 32 + (ln & 15)];
    float cn1 = nlds[sl * 32 + 16 + (ln & 15)];

    // bf16x3 MFMA: hi*hi and cross terms as independent chains
    f32x4 aH[2], aX[2];
#pragma unroll
    for (int cg = 0; cg < 2; ++cg) { aH[cg] = (f32x4){0,0,0,0}; aX[cg] = (f32x4){0,0,0,0}; }
#pragma unroll
    for (int kc = 0; kc < KC; ++kc) {
      bf16x8 bh0 = ldfrag<F>(hi, 0,  kc, ln);
      bf16x8 bh1 = ldfrag<F>(hi, 16, kc, ln);
      bf16x8 bl0 = ldfrag<F>(lo, 0,  kc, ln);
      bf16x8 bl1 = ldfrag<F>(lo, 16, kc, ln);
      aH[0] = __builtin_amdgcn_mfma_f32_16x16x32_bf16(ah[kc], bh0, aH[0], 0, 0, 0);
      aH[1] = __builtin_amdgcn_mfma_f32_16x16x32_bf16(ah[kc], bh1, aH[1], 0, 0, 0);
      aX[0] = __builtin_amdgcn_mfma_f32_16x16x32_bf16(al[kc], bh0, aX[0], 0, 0, 0);
      aX[1] = __builtin_amdgcn_mfma_f32_16x16x32_bf16(al[kc], bh1, aX[1], 0, 0, 0);
      aX[0] = __builtin_amdgcn_mfma_f32_16x16x32_bf16(ah[kc], bl0, aX[0], 0, 0, 0);
      aX[1] = __builtin_amdgcn_mfma_f32_16x16x32_bf16(ah[kc], bl1, aX[1], 0, 0, 0);
    }

    // selection: parallel appends per (cg, r) ballot group
#pragma unroll
    for (int cg = 0; cg < 2; ++cg) {
#pragma unroll
      for (int r = 0; r < 4; ++r) {
        float cnv = (cg == 0) ? cn0 : cn1;
        float s = cnv - 2.0f * (aH[cg][r] + aX[cg][r]);
        unsigned long long m = __ballot(s < myth[r]);
        if (m) {
          int qk = ((ln & 48) >> 2) + r;            // (ln>>4)*4 + r
          int basec = __shfl(bcnt, qk);
          if (s < myth[r]) {
            int pos = basec +
                __popcll(m & (0xFFFFull << (ln & 48)) & ((1ull << ln) - 1));
            int brow = (wv * 16 + qk) * LIST;
            Bs[brow + pos] = s;
            Bi[brow + pos] = (ushort)(cbase + c0 + cg * 16 + (ln & 15));
          }
          if (ln < 16 && (ln & 3) == r)
            bcnt += __popcll((m >> ((ln >> 2) * 16)) & 0xFFFFull);
        }
      }
      // overflow merges: post-cg counts <= 32 (=cap); fold any > 16
      unsigned long long mm = __ballot(ln < 16 && bcnt > 16);
      if (mm) {
        do {
          int qk = __ffsll(mm) - 1;
          mm &= mm - 1;
          merge_q(qk);
        } while (mm);
#pragma unroll
        for (int rr = 0; rr < 4; ++rr) myth[rr] = __shfl(thr_reg, ((ln & 48) >> 2) + rr);
      }
    }

    // counted drain: stage(t+1)+norms done; stage(t+2) stays in flight
    if (t + 2 < NT) wait_vm<LPSN>(); else wait_vm<0>();
  }

  // final flush of remaining buffered survivors
  {
    unsigned long long mm = __ballot(ln < 16 && bcnt > 0);
    while (mm) {
      int qk = __ffsll(mm) - 1;
      mm &= mm - 1;
      merge_q(qk);
    }
  }

#pragma unroll 1
  for (int k = 0; k < 16; ++k) {
    int q = wv * 16 + k;
    if (ln < LIST)
      out_cand[(size_t)(q0 + q) * (2 * LIST) + hf * LIST + ln] = (int)Li[q * LIST + ln];
  }
}

// Exact fp32 re-rank of the 64 union candidates -> true fp32 top-20 set.
template<int F>
__global__ __launch_bounds__(256) void refine_kernel(const float* __restrict__ X,
                                                     const float* __restrict__ sqn,
                                                     const int* __restrict__ cand,
                                                     int* __restrict__ out_idx) {
  const int wv = threadIdx.x >> 6, ln = threadIdx.x & 63;
  const int q = blockIdx.x * 4 + wv;
  int ci = cand[(size_t)q * (2 * LIST) + ln];
  const float* qrow = X + (size_t)q * F;
  const float* crow = X + (size_t)ci * F;
  float dot = 0.f;
#pragma unroll
  for (int d = 0; d < F; d += 4) {
    float4 qv = *(const float4*)(qrow + d);
    float4 cv = *(const float4*)(crow + d);
    dot += qv.x * cv.x + qv.y * cv.y + qv.z * cv.z + qv.w * cv.w;
  }
  float s = sqn[ci] - 2.0f * dot;
  int rank = 0;
#pragma unroll 1
  for (int j = 0; j < 64; ++j) {
    float sj = __shfl(s, j);
    int   cj = __shfl(ci, j);
    rank += (sj < s) || (sj == s && cj < ci);
  }
  if (rank < KNN) out_idx[(size_t)q * KNN + rank] = ci;
}

// x1 = relu(pos @ W1 + b1) + bf16 hi/lo split + squared row norms.
__global__ __launch_bounds__(256) void mlp1_kernel(const float* __restrict__ pos,
                                                   const float* __restrict__ W1,
                                                   const float* __restrict__ b1,
                                                   float* __restrict__ x1,
                                                   ushort* __restrict__ xh,
                                                   ushort* __restrict__ xl,
                                                   float* __restrict__ sqn) {
  int i = blockIdx.x * 4 + (threadIdx.x >> 6);
  int o = threadIdx.x & 63;
  float p0 = pos[i * 3], p1 = pos[i * 3 + 1], p2 = pos[i * 3 + 2];
  float v = p0 * W1[o] + p1 * W1[64 + o] + p2 * W1[128 + o] + b1[o];
  v = fmaxf(v, 0.f);
  x1[(size_t)i * 64 + o] = v;
  __hip_bfloat16 h = __float2bfloat16(v);
  float hv = __bfloat162float(h);
  __hip_bfloat16 l2 = __float2bfloat16(v - hv);
  xh[(size_t)i * 64 + o] = *(ushort*)&h;
  xl[(size_t)i * 64 + o] = *(ushort*)&l2;
  float ss = v * v;
#pragma unroll
  for (int d = 32; d; d >>= 1) ss += __shfl_xor(ss, d);
  if (o == 0) sqn[i] = ss;
}

// hi/lo bf16 split + squared norms for an existing fp32 feature array.
template<int F>
__global__ __launch_bounds__(256) void prep_kernel(const float* __restrict__ x,
                                                   ushort* __restrict__ xh,
                                                   ushort* __restrict__ xl,
                                                   float* __restrict__ sqn) {
  int i = blockIdx.x * 4 + (threadIdx.x >> 6);
  int l = threadIdx.x & 63;
  float ss = 0.f;
#pragma unroll
  for (int d = l; d < F; d += 64) {
    float v = x[(size_t)i * F + d];
    ss += v * v;
    __hip_bfloat16 h = __float2bfloat16(v);
    float hv = __bfloat162float(h);
    __hip_bfloat16 l2 = __float2bfloat16(v - hv);
    xh[(size_t)i * F + d] = *(ushort*)&h;
    xl[(size_t)i * F + d] = *(ushort*)&l2;
  }
#pragma unroll
  for (int d = 32; d; d >>= 1) ss += __shfl_xor(ss, d);
  if (l == 0) sqn[i] = ss;
}

// C[N x OUT] = X[N x K] @ W[K x OUT] (+ bias). Register-tiled 4 rows x float4.
template<int K, int OUT, bool BIAS>
__global__ __launch_bounds__(256) void lin_kernel(const float* __restrict__ X,
                                                  const float* __restrict__ W,
                                                  const float* __restrict__ bias,
                                                  float* __restrict__ C) {
  constexpr int XD = OUT / 4;
  constexpr int YD = 256 / XD;
  constexpr int R = YD * 4;
  __shared__ float xs[R * K];
  const int tid = threadIdx.x;
  const int tx = tid % XD, ty = tid / XD;
  const size_t r0 = (size_t)blockIdx.x * R;
  const float4* Xv = (const float4*)(X + r0 * K);
  float4* xsv = (float4*)xs;
#pragma unroll
  for (int i2 = tid; i2 < R * K / 4; i2 += 256) xsv[i2] = Xv[i2];
  __syncthreads();
  float4 acc[4];
#pragma unroll
  for (int i = 0; i < 4; i++) acc[i] = make_float4(0.f, 0.f, 0.f, 0.f);
  const float4* W4 = (const float4*)W;
#pragma unroll 8
  for (int k = 0; k < K; ++k) {
    float4 wv = W4[k * XD + tx];
#pragma unroll
    for (int i = 0; i < 4; i++) {
      float xv = xs[(ty * 4 + i) * K + k];
      acc[i].x += xv * wv.x; acc[i].y += xv * wv.y;
      acc[i].z += xv * wv.z; acc[i].w += xv * wv.w;
    }
  }
  float4 bv = make_float4(0.f, 0.f, 0.f, 0.f);
  if (BIAS) bv = ((const float4*)bias)[tx];
#pragma unroll
  for (int i = 0; i < 4; i++) {
    float4 o;
    o.x = acc[i].x + bv.x; o.y = acc[i].y + bv.y;
    o.z = acc[i].z + bv.z; o.w = acc[i].w + bv.w;
    ((float4*)(C + (r0 + ty * 4 + i) * OUT))[tx] = o;
  }
}

// out_i = relu(P_i + max_j Q[idx[i][j]])
template<int OUT>
__global__ void maxpool_kernel(const float* __restrict__ P, const float* __restrict__ Q,
                               const int* __restrict__ idx, float* __restrict__ xo) {
  __shared__ int nb[KNN];
  int i = blockIdx.x;
  if (threadIdx.x < KNN) nb[threadIdx.x] = idx[(size_t)i * KNN + threadIdx.x];
  __syncthreads();
  int o = threadIdx.x;
  float m = -3.0e38f;
#pragma unroll
  for (int j = 0; j < KNN; j++) m = fmaxf(m, Q[(size_t)nb[j] * OUT + o]);
  float p = P[(size_t)i * OUT + o];
  xo[(size_t)i * OUT + o] = fmaxf(p + m, 0.f);
}

// Wp[k][o] = We[k][o] - We[K+k][o]
__global__ void wsub_kernel(const float* __restrict__ We, float* __restrict__ Wp, int total) {
  int t = blockIdx.x * 256 + threadIdx.x;
  if (t < total) Wp[t] = We[t] - We[total + t];
}

extern "C" void kernel_launch(void* const* d_in, const int* in_sizes, int n_in,
                              void* d_out, int out_size, void* d_ws, size_t ws_size,
                              hipStream_t stream) {
  const float* pos = (const float*)d_in[0];
  const float* W1  = (const float*)d_in[1];
  const float* b1  = (const float*)d_in[2];
  const float* We1 = (const float*)d_in[3];
  const float* be1 = (const float*)d_in[4];
  const float* We2 = (const float*)d_in[5];
  const float* be2 = (const float*)d_in[6];
  const float* W2  = (const float*)d_in[7];
  const float* b2  = (const float*)d_in[8];
  float* out = (float*)d_out;

  const size_t N = N_PTS;
  float* ws  = (float*)d_ws;
  float* x1  = ws;               // N*64
  float* P1  = x1 + N * 64;      // N*128
  float* Q1  = P1 + N * 128;     // N*128
  float* x2  = Q1 + N * 128;     // N*128
  float* P2  = x2 + N * 128;     // N*256
  float* Q2  = P2 + N * 256;     // N*256
  float* x3  = Q2 + N * 256;     // N*256
  float* sqn = x3 + N * 256;     // N (x1 norms, then x2 norms)
  float* Wp1 = sqn + N;          // 64*128
  float* Wp2 = Wp1 + 64 * 128;   // 128*256
  int* idx1  = (int*)(Wp2 + 128 * 256);  // N*20
  int* idx2  = idx1 + N * KNN;           // N*20
  int* cand  = idx2 + N * KNN;           // N*64 (two half-lists, reused per layer)
  ushort* X1h = (ushort*)(cand + N * 2 * LIST); // N*64
  ushort* X1l = X1h + N * 64;               // N*64
  ushort* X2h = X1l + N * 64;               // N*128
  ushort* X2l = X2h + N * 128;              // N*128
  size_t need = (size_t)((char*)(X2l + N * 128) - (char*)d_ws);
  if (ws_size < need) return;  // insufficient scratch -> visible failure

  auto lds_bytes = [](int F) {
    // 3 tile slots (hi+lo) + 3x32 norms + Bs + Bi + Ld + Li
    return (size_t)(3 * 2 * 32 * F) * 2 + 3 * 32 * 4 +
           (size_t)(64 * LIST) * 4 + (size_t)(64 * LIST) * 2 +
           (size_t)(64 * LIST) * 4 + (size_t)(64 * LIST) * 2;
  };
  size_t lds64 = lds_bytes(64), lds128 = lds_bytes(128);
  hipFuncSetAttribute(reinterpret_cast<const void*>(&knn_kernel<64>),
                      hipFuncAttributeMaxDynamicSharedMemorySize, (int)lds64);
  hipFuncSetAttribute(reinterpret_cast<const void*>(&knn_kernel<128>),
                      hipFuncAttributeMaxDynamicSharedMemorySize, (int)lds128);

  wsub_kernel<<<(64 * 128 + 255) / 256, 256, 0, stream>>>(We1, Wp1, 64 * 128);
  wsub_kernel<<<(128 * 256 + 255) / 256, 256, 0, stream>>>(We2, Wp2, 128 * 256);

  mlp1_kernel<<<N / 4, 256, 0, stream>>>(pos, W1, b1, x1, X1h, X1l, sqn);
  knn_kernel<64><<<N / 32, 256, lds64, stream>>>(X1h, X1l, sqn, cand);   // 512 blocks
  refine_kernel<64><<<N / 4, 256, 0, stream>>>(x1, sqn, cand, idx1);
  lin_kernel<64, 128, true ><<<N / 32, 256, 0, stream>>>(x1, Wp1, be1, P1);
  lin_kernel<64, 128, false><<<N / 32, 256, 0, stream>>>(x1, We1 + 64 * 128, nullptr, Q1);
  maxpool_kernel<128><<<N, 128, 0, stream>>>(P1, Q1, idx1, x2);

  prep_kernel<128><<<N / 4, 256, 0, stream>>>(x2, X2h, X2l, sqn);
  knn_kernel<128><<<N / 32, 256, lds128, stream>>>(X2h, X2l, sqn, cand); // 512 blocks
  refine_kernel<128><<<N / 4, 256, 0, stream>>>(x2, sqn, cand, idx2);
  lin_kernel<128, 256, true ><<<N / 16, 256, 0, stream>>>(x2, Wp2, be2, P2);
  lin_kernel<128, 256, false><<<N / 16, 256, 0, stream>>>(x2, We2 + 128 * 256, nullptr, Q2);
  maxpool_kernel<256><<<N, 256, 0, stream>>>(P2, Q2, idx2, x3);

  lin_kernel<256, 128, true ><<<N / 32, 256, 0, stream>>>(x3, W2, b2, out);
}

// Round 8
// 2124.609 us; speedup vs baseline: 1.4474x; 1.0056x over previous
//
#include <hip/hip_runtime.h>
#include <hip/hip_bf16.h>

#define N_PTS 16384
#define KNN   20
#define LIST  32   // approx-stage list width per candidate-quarter (refine is exact)
#define NSPLIT 4   // candidate-range split

typedef __attribute__((ext_vector_type(8))) short bf16x8;
typedef __attribute__((ext_vector_type(4))) float f32x4;

// Load B fragments (16 candidate rows x 32k-chunk) for one tile, direct
// global -> registers. Row = c0 + (ln&15), chunk = kc*4 + (ln>>4).
template<int F>
__device__ __forceinline__ void load_B(const ushort* __restrict__ Xh,
                                       const ushort* __restrict__ Xl,
                                       const float* __restrict__ sqn,
                                       int c0, int ln,
                                       bf16x8 (&bh)[F / 32], bf16x8 (&bl)[F / 32],
                                       float& cn) {
  constexpr int KC = F / 32;
  const int apc = ln >> 4;
  size_t roff = (size_t)(c0 + (ln & 15)) * F;
#pragma unroll
  for (int kc = 0; kc < KC; ++kc) {
    size_t off = roff + (size_t)(kc * 4 + apc) * 8;
    bh[kc] = *(const bf16x8*)(Xh + off);
    bl[kc] = *(const bf16x8*)(Xl + off);
  }
  cn = sqn[c0 + (ln & 15)];
}

// Fused bf16x3-MFMA distance + buffered top-32 kNN over a QUARTER of the
// candidate range. ONE wave per block (64 thr), 32 queries per wave (two
// 16-row A groups sharing every B fragment). Candidates stream global->reg
// (L2-resident, no LDS staging, NO barriers). Selection: parallel survivor
// appends into per-query LDS buffers + rare wave-collective bitonic merges.
template<int F>
__global__ __launch_bounds__(64, 2) void knn_kernel(const ushort* __restrict__ Xh,
                                                    const ushort* __restrict__ Xl,
                                                    const float* __restrict__ sqn,
                                                    int* __restrict__ out_cand) {
  constexpr int KC = F / 32;            // 32-k chunks per row
  constexpr int NC = N_PTS / NSPLIT;    // candidates per block
  constexpr int TS = 16;                // candidate tile (one MFMA column tile)
  constexpr int NT = NC / TS;
  __shared__ float  Bs[32 * LIST];      // survivor scores
  __shared__ ushort Bi[32 * LIST];      // survivor indices
  __shared__ float  Ld[32 * LIST];      // sorted distances
  __shared__ ushort Li[32 * LIST];      // sorted indices

  const int ln = threadIdx.x;
  const int q0 = (int)(blockIdx.x >> 2) * 32;
  const int hf = blockIdx.x & 3;
  const int cbase = hf * NC;

  // init sorted lists (32 queries x 32 entries)
#pragma unroll
  for (int k = 0; k < 16; ++k) {
    int idx = k * 64 + ln;
    Ld[idx] = 3.0e38f; Li[idx] = 0;
  }
  float thr_reg = 3.0e38f;   // lane j<32: 32nd-best of query j
  float myth[8];             // own-score thresholds: [qg*4+r] for q=qg*16+(ln>>4)*4+r
#pragma unroll
  for (int i = 0; i < 8; ++i) myth[i] = 3.0e38f;
  int bcnt = 0;              // lane j<32: buffered count of query j

  // wave-collective merge of query qk's buffer into its sorted top-32
  auto merge_q = [&](int qk) {
    int cnt = __shfl(bcnt, qk);
    int lrow = qk * LIST;
    float key; int id;
    if (ln < 32) { key = Ld[lrow + ln]; id = (int)Li[lrow + ln]; }
    else {
      int j = ln - 32;
      bool v = j < cnt;
      key = v ? Bs[lrow + j] : 3.0e38f;
      id  = v ? (int)Bi[lrow + j] : 65535;
    }
#pragma unroll
    for (int kk = 2; kk <= 64; kk <<= 1) {
#pragma unroll
      for (int jj = kk >> 1; jj > 0; jj >>= 1) {
        float ok = __shfl_xor(key, jj);
        int   oi = __shfl_xor(id, jj);
        bool pless = (ok < key) || (ok == key && oi < id);
        bool take = pless == (((ln & jj) == 0) == ((ln & kk) == 0));
        key = take ? ok : key;
        id  = take ? oi : id;
      }
    }
    if (ln < 32) { Ld[lrow + ln] = key; Li[lrow + ln] = (ushort)id; }
    float tnew = __shfl(key, 31);
    thr_reg = (ln == qk) ? tnew : thr_reg;
    bcnt    = (ln == qk) ? 0 : bcnt;
  };

  // A fragments: 2 query groups x KC chunks, hi/lo — direct from global
  bf16x8 ah[2][KC], al[2][KC];
  {
    const int apc = ln >> 4;
#pragma unroll
    for (int qg = 0; qg < 2; ++qg)
#pragma unroll
      for (int kc = 0; kc < KC; ++kc) {
        size_t off = (size_t)(q0 + qg * 16 + (ln & 15)) * F + (size_t)(kc * 4 + apc) * 8;
        ah[qg][kc] = *(const bf16x8*)(Xh + off);
        al[qg][kc] = *(const bf16x8*)(Xl + off);
      }
  }

  // register double-buffered B tiles (named sets — no runtime indexing)
  bf16x8 b0h[KC], b0l[KC], b1h[KC], b1l[KC];
  float cn0, cn1;
  load_B<F>(Xh, Xl, sqn, cbase, ln, b0h, b0l, cn0);
  load_B<F>(Xh, Xl, sqn, cbase + TS, ln, b1h, b1l, cn1);

  // one pipeline step: MFMA(tile t from bh/bl) -> scores -> reload(t+2) ->
  // selection. Loads for t+2 fly across the whole next step (>= L2 latency).
  auto step = [&](bf16x8 (&bh)[KC], bf16x8 (&bl)[KC], float& cn, int t) {
    f32x4 aH[2], aX[2];
#pragma unroll
    for (int qg = 0; qg < 2; ++qg) { aH[qg] = (f32x4){0,0,0,0}; aX[qg] = (f32x4){0,0,0,0}; }
#pragma unroll
    for (int kc = 0; kc < KC; ++kc) {
#pragma unroll
      for (int qg = 0; qg < 2; ++qg) {
        aH[qg] = __builtin_amdgcn_mfma_f32_16x16x32_bf16(ah[qg][kc], bh[kc], aH[qg], 0, 0, 0);
        aX[qg] = __builtin_amdgcn_mfma_f32_16x16x32_bf16(al[qg][kc], bh[kc], aX[qg], 0, 0, 0);
        aX[qg] = __builtin_amdgcn_mfma_f32_16x16x32_bf16(ah[qg][kc], bl[kc], aX[qg], 0, 0, 0);
      }
    }
    // scores for this lane: query qg*16+(ln>>4)*4+r, cand t*TS+(ln&15)
    float s8[8];
#pragma unroll
    for (int qg = 0; qg < 2; ++qg)
#pragma unroll
      for (int r = 0; r < 4; ++r)
        s8[qg * 4 + r] = cn - 2.0f * (aH[qg][r] + aX[qg][r]);

    // reload this register set for tile t+2 (covers latency under selection+next MFMA)
    if (t + 2 < NT) load_B<F>(Xh, Xl, sqn, cbase + (t + 2) * TS, ln, bh, bl, cn);

    // selection: 8 disjoint-query ballot groups, parallel appends
    const int ci = cbase + t * TS + (ln & 15);
#pragma unroll
    for (int qg = 0; qg < 2; ++qg)
#pragma unroll
      for (int r = 0; r < 4; ++r) {
        float s = s8[qg * 4 + r];
        unsigned long long m = __ballot(s < myth[qg * 4 + r]);
        if (m) {
          int qk = qg * 16 + ((ln & 48) >> 2) + r;
          int basec = __shfl(bcnt, qk);
          if (s < myth[qg * 4 + r]) {
            int pos = basec +
                __popcll(m & (0xFFFFull << (ln & 48)) & ((1ull << ln) - 1));
            Bs[qk * LIST + pos] = s;
            Bi[qk * LIST + pos] = (ushort)ci;
          }
          if (ln < 32 && (ln >> 4) == qg && (ln & 3) == r)
            bcnt += __popcll((m >> (((ln & 15) >> 2) * 16)) & 0xFFFFull);
        }
      }
    // overflow merges once per step: per-query appends/step <= 16, cap 32
    unsigned long long mm = __ballot(ln < 32 && bcnt > 16);
    if (mm) {
      do {
        int qk = __ffsll(mm) - 1;
        mm &= mm - 1;
        merge_q(qk);
      } while (mm);
#pragma unroll
      for (int qg = 0; qg < 2; ++qg)
#pragma unroll
        for (int r = 0; r < 4; ++r)
          myth[qg * 4 + r] = __shfl(thr_reg, qg * 16 + ((ln & 48) >> 2) + r);
    }
  };

#pragma unroll 1
  for (int t = 0; t < NT; t += 2) {
    step(b0h, b0l, cn0, t);
    step(b1h, b1l, cn1, t + 1);
  }

  // final flush
  {
    unsigned long long mm = __ballot(ln < 32 && bcnt > 0);
    while (mm) {
      int qk = __ffsll(mm) - 1;
      mm &= mm - 1;
      merge_q(qk);
    }
  }

  // write 32 queries x 32 candidates
#pragma unroll
  for (int k2 = 0; k2 < 16; ++k2) {
    int row = k2 * 2 + (ln >> 5);
    int col = ln & 31;
    out_cand[(size_t)(q0 + row) * (NSPLIT * LIST) + hf * LIST + col] = (int)Li[row * LIST + col];
  }
}

// Exact fp32 re-rank of the 128 union candidates -> true fp32 top-20 set.
// One wave per query; lane l handles candidates l and l+64.
template<int F>
__global__ __launch_bounds__(256) void refine_kernel(const float* __restrict__ X,
                                                     const float* __restrict__ sqn,
                                                     const int* __restrict__ cand,
                                                     int* __restrict__ out_idx) {
  constexpr int CW = NSPLIT * LIST;  // 128
  const int wv = threadIdx.x >> 6, ln = threadIdx.x & 63;
  const int q = blockIdx.x * 4 + wv;
  int c0 = cand[(size_t)q * CW + ln];
  int c1 = cand[(size_t)q * CW + 64 + ln];
  const float* qrow = X + (size_t)q * F;
  const float* crow0 = X + (size_t)c0 * F;
  const float* crow1 = X + (size_t)c1 * F;
  float dot0 = 0.f, dot1 = 0.f;
#pragma unroll
  for (int d = 0; d < F; d += 4) {
    float4 qv = *(const float4*)(qrow + d);
    float4 v0 = *(const float4*)(crow0 + d);
    float4 v1 = *(const float4*)(crow1 + d);
    dot0 += qv.x * v0.x + qv.y * v0.y + qv.z * v0.z + qv.w * v0.w;
    dot1 += qv.x * v1.x + qv.y * v1.y + qv.z * v1.z + qv.w * v1.w;
  }
  float s0 = sqn[c0] - 2.0f * dot0;
  float s1 = sqn[c1] - 2.0f * dot1;
  // rank by (score asc, index asc); quarters are disjoint -> no duplicates
  int rank0 = 0, rank1 = 0;
#pragma unroll 1
  for (int j = 0; j < 64; ++j) {
    float a0 = __shfl(s0, j); int i0 = __shfl(c0, j);
    float a1 = __shfl(s1, j); int i1 = __shfl(c1, j);
    rank0 += ((a0 < s0) || (a0 == s0 && i0 < c0)) + ((a1 < s0) || (a1 == s0 && i1 < c0));
    rank1 += ((a0 < s1) || (a0 == s1 && i0 < c1)) + ((a1 < s1) || (a1 == s1 && i1 < c1));
  }
  if (rank0 < KNN) out_idx[(size_t)q * KNN + rank0] = c0;
  if (rank1 < KNN) out_idx[(size_t)q * KNN + rank1] = c1;
}

// x1 = relu(pos @ W1 + b1) + bf16 hi/lo split + squared row norms.
__global__ __launch_bounds__(256) void mlp1_kernel(const float* __restrict__ pos,
                                                   const float* __restrict__ W1,
                                                   const float* __restrict__ b1,
                                                   float* __restrict__ x1,
                                                   ushort* __restrict__ xh,
                                                   ushort* __restrict__ xl,
                                                   float* __restrict__ sqn) {
  int i = blockIdx.x * 4 + (threadIdx.x >> 6);
  int o = threadIdx.x & 63;
  float p0 = pos[i * 3], p1 = pos[i * 3 + 1], p2 = pos[i * 3 + 2];
  float v = p0 * W1[o] + p1 * W1[64 + o] + p2 * W1[128 + o] + b1[o];
  v = fmaxf(v, 0.f);
  x1[(size_t)i * 64 + o] = v;
  __hip_bfloat16 h = __float2bfloat16(v);
  float hv = __bfloat162float(h);
  __hip_bfloat16 l2 = __float2bfloat16(v - hv);
  xh[(size_t)i * 64 + o] = *(ushort*)&h;
  xl[(size_t)i * 64 + o] = *(ushort*)&l2;
  float ss = v * v;
#pragma unroll
  for (int d = 32; d; d >>= 1) ss += __shfl_xor(ss, d);
  if (o == 0) sqn[i] = ss;
}

// hi/lo bf16 split + squared norms for an existing fp32 feature array.
template<int F>
__global__ __launch_bounds__(256) void prep_kernel(const float* __restrict__ x,
                                                   ushort* __restrict__ xh,
                                                   ushort* __restrict__ xl,
                                                   float* __restrict__ sqn) {
  int i = blockIdx.x * 4 + (threadIdx.x >> 6);
  int l = threadIdx.x & 63;
  float ss = 0.f;
#pragma unroll
  for (int d = l; d < F; d += 64) {
    float v = x[(size_t)i * F + d];
    ss += v * v;
    __hip_bfloat16 h = __float2bfloat16(v);
    float hv = __bfloat162float(h);
    __hip_bfloat16 l2 = __float2bfloat16(v - hv);
    xh[(size_t)i * F + d] = *(ushort*)&h;
    xl[(size_t)i * F + d] = *(ushort*)&l2;
  }
#pragma unroll
  for (int d = 32; d; d >>= 1) ss += __shfl_xor(ss, d);
  if (l == 0) sqn[i] = ss;
}

// C[N x OUT] = X[N x K] @ W[K x OUT] (+ bias). Register-tiled 4 rows x float4.
template<int K, int OUT, bool BIAS>
__global__ __launch_bounds__(256) void lin_kernel(const float* __restrict__ X,
                                                  const float* __restrict__ W,
                                                  const float* __restrict__ bias,
                                                  float* __restrict__ C) {
  constexpr int XD = OUT / 4;
  constexpr int YD = 256 / XD;
  constexpr int R = YD * 4;
  __shared__ float xs[R * K];
  const int tid = threadIdx.x;
  const int tx = tid % XD, ty = tid / XD;
  const size_t r0 = (size_t)blockIdx.x * R;
  const float4* Xv = (const float4*)(X + r0 * K);
  float4* xsv = (float4*)xs;
#pragma unroll
  for (int i2 = tid; i2 < R * K / 4; i2 += 256) xsv[i2] = Xv[i2];
  __syncthreads();
  float4 acc[4];
#pragma unroll
  for (int i = 0; i < 4; i++) acc[i] = make_float4(0.f, 0.f, 0.f, 0.f);
  const float4* W4 = (const float4*)W;
#pragma unroll 8
  for (int k = 0; k < K; ++k) {
    float4 wv = W4[k * XD + tx];
#pragma unroll
    for (int i = 0; i < 4; i++) {
      float xv = xs[(ty * 4 + i) * K + k];
      acc[i].x += xv * wv.x; acc[i].y += xv * wv.y;
      acc[i].z += xv * wv.z; acc[i].w += xv * wv.w;
    }
  }
  float4 bv = make_float4(0.f, 0.f, 0.f, 0.f);
  if (BIAS) bv = ((const float4*)bias)[tx];
#pragma unroll
  for (int i = 0; i < 4; i++) {
    float4 o;
    o.x = acc[i].x + bv.x; o.y = acc[i].y + bv.y;
    o.z = acc[i].z + bv.z; o.w = acc[i].w + bv.w;
    ((float4*)(C + (r0 + ty * 4 + i) * OUT))[tx] = o;
  }
}

// out_i = relu(P_i + max_j Q[idx[i][j]])
template<int OUT>
__global__ void maxpool_kernel(const float* __restrict__ P, const float* __restrict__ Q,
                               const int* __restrict__ idx, float* __restrict__ xo) {
  __shared__ int nb[KNN];
  int i = blockIdx.x;
  if (threadIdx.x < KNN) nb[threadIdx.x] = idx[(size_t)i * KNN + threadIdx.x];
  __syncthreads();
  int o = threadIdx.x;
  float m = -3.0e38f;
#pragma unroll
  for (int j = 0; j < KNN; j++) m = fmaxf(m, Q[(size_t)nb[j] * OUT + o]);
  float p = P[(size_t)i * OUT + o];
  xo[(size_t)i * OUT + o] = fmaxf(p + m, 0.f);
}

// Wp[k][o] = We[k][o] - We[K+k][o]
__global__ void wsub_kernel(const float* __restrict__ We, float* __restrict__ Wp, int total) {
  int t = blockIdx.x * 256 + threadIdx.x;
  if (t < total) Wp[t] = We[t] - We[total + t];
}

extern "C" void kernel_launch(void* const* d_in, const int* in_sizes, int n_in,
                              void* d_out, int out_size, void* d_ws, size_t ws_size,
                              hipStream_t stream) {
  const float* pos = (const float*)d_in[0];
  const float* W1  = (const float*)d_in[1];
  const float* b1  = (const float*)d_in[2];
  const float* We1 = (const float*)d_in[3];
  const float* be1 = (const float*)d_in[4];
  const float* We2 = (const float*)d_in[5];
  const float* be2 = (const float*)d_in[6];
  const float* W2  = (const float*)d_in[7];
  const float* b2  = (const float*)d_in[8];
  float* out = (float*)d_out;

  const size_t N = N_PTS;
  float* ws  = (float*)d_ws;
  float* x1  = ws;               // N*64
  float* P1  = x1 + N * 64;      // N*128
  float* Q1  = P1 + N * 128;     // N*128
  float* x2  = Q1 + N * 128;     // N*128
  float* P2  = x2 + N * 128;     // N*256
  float* Q2  = P2 + N * 256;     // N*256
  float* x3  = Q2 + N * 256;     // N*256
  float* sqn = x3 + N * 256;     // N (x1 norms, then x2 norms)
  float* Wp1 = sqn + N;          // 64*128
  float* Wp2 = Wp1 + 64 * 128;   // 128*256
  int* idx1  = (int*)(Wp2 + 128 * 256);  // N*20
  int* idx2  = idx1 + N * KNN;           // N*20
  // cand aliases Q2's slot (N*128 ints <= N*256 floats): fully consumed by
  // refine before Q2 is written by lin_kernel (same stream, program order).
  int* cand  = (int*)Q2;
  ushort* X1h = (ushort*)(idx2 + N * KNN);  // N*64
  ushort* X1l = X1h + N * 64;               // N*64
  ushort* X2h = X1l + N * 64;               // N*128
  ushort* X2l = X2h + N * 128;              // N*128
  size_t need = (size_t)((char*)(X2l + N * 128) - (char*)d_ws);
  if (ws_size < need) return;  // insufficient scratch -> visible failure

  wsub_kernel<<<(64 * 128 + 255) / 256, 256, 0, stream>>>(We1, Wp1, 64 * 128);
  wsub_kernel<<<(128 * 256 + 255) / 256, 256, 0, stream>>>(We2, Wp2, 128 * 256);

  mlp1_kernel<<<N / 4, 256, 0, stream>>>(pos, W1, b1, x1, X1h, X1l, sqn);
  knn_kernel<64><<<(N / 32) * NSPLIT, 64, 0, stream>>>(X1h, X1l, sqn, cand);   // 2048 blocks
  refine_kernel<64><<<N / 4, 256, 0, stream>>>(x1, sqn, cand, idx1);
  lin_kernel<64, 128, true ><<<N / 32, 256, 0, stream>>>(x1, Wp1, be1, P1);
  lin_kernel<64, 128, false><<<N / 32, 256, 0, stream>>>(x1, We1 + 64 * 128, nullptr, Q1);
  maxpool_kernel<128><<<N, 128, 0, stream>>>(P1, Q1, idx1, x2);

  prep_kernel<128><<<N / 4, 256, 0, stream>>>(x2, X2h, X2l, sqn);
  knn_kernel<128><<<(N / 32) * NSPLIT, 64, 0, stream>>>(X2h, X2l, sqn, cand);  // 2048 blocks
  refine_kernel<128><<<N / 4, 256, 0, stream>>>(x2, sqn, cand, idx2);
  lin_kernel<128, 256, true ><<<N / 16, 256, 0, stream>>>(x2, Wp2, be2, P2);
  lin_kernel<128, 256, false><<<N / 16, 256, 0, stream>>>(x2, We2 + 128 * 256, nullptr, Q2);
  maxpool_kernel<256><<<N, 256, 0, stream>>>(P2, Q2, idx2, x3);

  lin_kernel<256, 128, true ><<<N / 32, 256, 0, stream>>>(x3, W2, b2, out);
}